// Round 15
// baseline (374.327 us; speedup 1.0000x reference)
//
#include <hip/hip_runtime.h>
#include <hip/hip_bf16.h>
#include <stdint.h>

// ---------------- problem constants ----------------
#define BATCH   16384
#define SDIM    128
#define ENCK    10
#define ADIM    32
#define DECK    10
#define HID     2048
#define KSPINE  1280      // SDIM*ENCK

typedef __bf16 bf16x8 __attribute__((ext_vector_type(8)));
typedef float  f32x4  __attribute__((ext_vector_type(4)));

typedef __attribute__((address_space(1))) const void kGlobalVoid;
typedef __attribute__((address_space(3))) void       kLdsVoid;

__device__ __forceinline__ unsigned short f2b(float f) {
  union { float f; unsigned u; } v; v.f = f;
  unsigned r = v.u + 0x7fffu + ((v.u >> 16) & 1u);   // RNE
  return (unsigned short)(r >> 16);
}

// weight-row permutation within each 64-row group: position q holds original row
// (q&15)*4 + (q>>4).  Makes acc[m][n]@lane lr own 4 CONSECUTIVE output cols lr*4+n.
__device__ __forceinline__ int permrow(int pr) {
  int q = pr & 63;
  return (pr & ~63) | (((q & 15) << 2) | (q >> 4));
}

// ---------------- single fused prep: encoder + permuted W1/W2 f2b + Weff + beff ----------------
#define ENC_BLKS  40960
#define W1_BLKS   5120
#define W2_BLKS   8192
#define WEFF_BLKS 256

__global__ __launch_bounds__(256) void prep_kernel(
    const float* __restrict__ state, const float* __restrict__ mean,
    const float* __restrict__ stdv,
    const float* __restrict__ W1, const float* __restrict__ W2,
    const float* __restrict__ W3, const float* __restrict__ Wd,
    const float* __restrict__ b3, const float* __restrict__ bd,
    unsigned* __restrict__ spine, unsigned* __restrict__ W1b,
    unsigned* __restrict__ W2b, unsigned short* __restrict__ Weff,
    float* __restrict__ beff) {
  int b = blockIdx.x, t = threadIdx.x;
  if (b < ENC_BLKS) {                    // encoder: one thread per (b,d,k-pair)
    int idx = b * 256 + t;
    int idx1 = (int)(((long long)idx * 0x66666667LL) >> 33);  // idx/5
    int kk = idx - idx1 * 5;
    int d  = idx1 & (SDIM - 1);
    float x = state[idx1];
    int mi = d * ENCK + kk * 2;
    float m0 = mean[mi], m1 = mean[mi + 1];
    float s0 = stdv[mi], s1 = stdv[mi + 1];
    float v0 = 1.f / (1.f + __expf((m0 - x) / s0));
    float v1 = 1.f / (1.f + __expf((m1 - x) / s1));
    spine[idx] = (unsigned)f2b(v0) | ((unsigned)f2b(v1) << 16);
  } else if (b < ENC_BLKS + W1_BLKS) {   // W1 -> bf16, permuted rows (640 dwords/row)
    int i = (b - ENC_BLKS) * 256 + t;
    int row = i / 640, c2 = i - row * 640;
    float2 v = reinterpret_cast<const float2*>(W1)[permrow(row) * 640 + c2];
    W1b[i] = (unsigned)f2b(v.x) | ((unsigned)f2b(v.y) << 16);
  } else if (b < ENC_BLKS + W1_BLKS + W2_BLKS) {   // W2 -> bf16, permuted (1024 dw/row)
    int i = (b - ENC_BLKS - W1_BLKS) * 256 + t;
    int row = i >> 10, c2 = i & 1023;
    float2 v = reinterpret_cast<const float2*>(W2)[permrow(row) * 1024 + c2];
    W2b[i] = (unsigned)f2b(v.x) | ((unsigned)f2b(v.y) << 16);
  } else if (b < ENC_BLKS + W1_BLKS + W2_BLKS + WEFF_BLKS) {   // Weff (natural)
    int idx = (b - ENC_BLKS - W1_BLKS - W2_BLKS) * 256 + t;
    int a = idx >> 11, j = idx & 2047;
    float s = 0.f;
#pragma unroll
    for (int k = 0; k < DECK; ++k)
      s += Wd[a * DECK + k] * W3[(size_t)(a * DECK + k) * HID + j];
    Weff[idx] = f2b(s);
  } else {                               // beff
    if (t < ADIM) {
      float s = bd[t];
#pragma unroll
      for (int k = 0; k < DECK; ++k) s += Wd[t * DECK + k] * b3[t * DECK + k];
      beff[t] = s;
    }
  }
}

// ---------------- shared GEMM machinery (R7/R11 structure) ----------------
#define A0B 0
#define B0B 32768
#define A1B 65536
#define B1B 98304

#define FENCE asm volatile("" ::: "memory")
#define SB0 __builtin_amdgcn_sched_barrier(0)
#define BAR __builtin_amdgcn_s_barrier()
#define LGKM0 do { asm volatile("s_waitcnt lgkmcnt(0)" ::: "memory"); SB0; } while (0)

#define STAGE(BASEPTR, R0A, R0B, LDS0, LDS1, KT)                                             \
  __builtin_amdgcn_global_load_lds((kGlobalVoid*)((BASEPTR) + (size_t)((R0A) + rs) * K + (KT) + ce), \
                                   (kLdsVoid*)(smem + (LDS0) + t * 16), 16, 0, 0);           \
  __builtin_amdgcn_global_load_lds((kGlobalVoid*)((BASEPTR) + (size_t)((R0B) + rs) * K + (KT) + ce), \
                                   (kLdsVoid*)(smem + (LDS1) + t * 16), 16, 0, 0);

#define DS_AF(DST, ABASE, MPN)                                                               \
  _Pragma("unroll")                                                                          \
  for (int j2 = 0; j2 < 2; ++j2) {                                                           \
    _Pragma("unroll")                                                                        \
    for (int ks = 0; ks < 2; ++ks) {                                                         \
      int rowl = wr * 128 + (MPN) * 32 + j2 * 16 + lr;                                       \
      DST[j2][ks] = *reinterpret_cast<const bf16x8*>(                                        \
          smem + (ABASE) + rowl * 128 + ((((ks) << 6) | (kh << 4)) ^ swz));                  \
    }                                                                                        \
  }

#define DS_B2(DST, NP, BBASE)                                                                \
  _Pragma("unroll")                                                                          \
  for (int ks = 0; ks < 2; ++ks) {                                                           \
    int rowl = wc * 64 + (NP) * 16 + lr;                                                     \
    DST[NP][ks] = *reinterpret_cast<const bf16x8*>(                                          \
        smem + (BBASE) + rowl * 128 + ((((ks) << 6) | (kh << 4)) ^ swz));                    \
  }

#define DS_BF(DST, BBASE)                                                                    \
  _Pragma("unroll")                                                                          \
  for (int n = 0; n < 4; ++n) {                                                              \
    _Pragma("unroll")                                                                        \
    for (int ks = 0; ks < 2; ++ks) {                                                         \
      int rowl = wc * 64 + n * 16 + lr;                                                      \
      DST[n][ks] = *reinterpret_cast<const bf16x8*>(                                         \
          smem + (BBASE) + rowl * 128 + ((((ks) << 6) | (kh << 4)) ^ swz));                  \
    }                                                                                        \
  }

#define MFMA16(MP, AF, BF)                                                                   \
  _Pragma("unroll")                                                                          \
  for (int j2 = 0; j2 < 2; ++j2)                                                             \
    _Pragma("unroll")                                                                        \
    for (int n = 0; n < 4; ++n)                                                              \
      _Pragma("unroll")                                                                      \
      for (int ks = 0; ks < 2; ++ks)                                                         \
        acc[(MP) * 2 + j2][n] = __builtin_amdgcn_mfma_f32_16x16x32_bf16(                     \
            AF[j2][ks], BF[n][ks], acc[(MP) * 2 + j2][n], 0, 0, 0);

#define SGB_PHASE                                                                            \
  __builtin_amdgcn_sched_group_barrier(0x8, 2, 0);                                           \
  __builtin_amdgcn_sched_group_barrier(0x100, 1, 0);                                         \
  __builtin_amdgcn_sched_group_barrier(0x8, 2, 0);                                           \
  __builtin_amdgcn_sched_group_barrier(0x100, 1, 0);                                         \
  __builtin_amdgcn_sched_group_barrier(0x20, 2, 0);                                          \
  __builtin_amdgcn_sched_group_barrier(0x8, 3, 0);                                           \
  __builtin_amdgcn_sched_group_barrier(0x100, 1, 0);                                         \
  __builtin_amdgcn_sched_group_barrier(0x8, 3, 0);                                           \
  __builtin_amdgcn_sched_group_barrier(0x100, 1, 0);                                         \
  __builtin_amdgcn_sched_group_barrier(0x8, 3, 0);                                           \
  __builtin_amdgcn_sched_group_barrier(0x100, 1, 0);                                         \
  __builtin_amdgcn_sched_group_barrier(0x8, 3, 0);                                           \
  __builtin_amdgcn_sched_group_barrier(0x100, 1, 0);

#define VM_NONE
#define VM2 asm volatile("s_waitcnt vmcnt(2)" ::: "memory"); SB0;
#define VM6 asm volatile("s_waitcnt vmcnt(6)" ::: "memory"); SB0;

#define PH(MP, AF_C, AF_N, BF_C, BF_N, NXT_A, NXT_MP, BBASE_N, VMW, STG)                     \
  do {                                                                                       \
    LGKM0;                                                                                   \
    VMW                                                                                      \
    __builtin_amdgcn_s_setprio(1);                                                           \
    MFMA16(MP, AF_C, BF_C);                                                                  \
    __builtin_amdgcn_s_setprio(0);                                                           \
    DS_AF(AF_N, NXT_A, NXT_MP);                                                              \
    DS_B2(BF_N, MP, BBASE_N);                                                                \
    STG;                                                                                     \
    SGB_PHASE;                                                                               \
    FENCE;                                                                                   \
    BAR;                                                                                     \
  } while (0)

// head + prologue + main K loop; leaves acc ready. Expects A, Bw, K, NI in scope.
#define GEMM_BODY                                                                            \
  __shared__ char smem[131072];                                                              \
  const int t    = threadIdx.x;                                                              \
  const int lane = t & 63;                                                                   \
  const int w    = t >> 6;                                                                   \
  const int wr   = w >> 2;                                                                   \
  const int wc   = w & 3;                                                                    \
  const int lr   = lane & 15;                                                                \
  const int kh   = lane >> 4;                                                                \
  const int swz  = (lr & 7) << 4;                                                            \
  const int rs   = t >> 3;                                                                   \
  const int ce   = ((t & 7) ^ (rs & 7)) << 3;                                                \
  const int bid = blockIdx.x;                                                                \
  const int xcd = bid & 7, idx = bid >> 3;                                                   \
  const int row0 = (xcd * 8 + (idx >> 3)) * 256;                                             \
  const int col0 = (idx & 7) * 256;                                                          \
  f32x4 acc[8][4];                                                                           \
  _Pragma("unroll")                                                                          \
  for (int m = 0; m < 8; ++m)                                                                \
    _Pragma("unroll")                                                                        \
    for (int n = 0; n < 4; ++n)                                                              \
      acc[m][n] = (f32x4){0.f, 0.f, 0.f, 0.f};                                               \
  bf16x8 afc[2][2], afn[2][2], bfA[4][2], bfB[4][2];                                         \
  STAGE(Bw, col0 + 0,   col0 + 64,  B0B + 0,     B0B + 8192,  0);                            \
  STAGE(Bw, col0 + 128, col0 + 192, B0B + 16384, B0B + 24576, 0);                            \
  STAGE(A,  row0 + 0,   row0 + 128, A0B + 0,     A0B + 16384, 0);                            \
  STAGE(A,  row0 + 64,  row0 + 192, A0B + 8192,  A0B + 24576, 0);                            \
  STAGE(Bw, col0 + 0,   col0 + 64,  B1B + 0,     B1B + 8192,  64);                           \
  STAGE(Bw, col0 + 128, col0 + 192, B1B + 16384, B1B + 24576, 64);                           \
  STAGE(A,  row0 + 0,   row0 + 128, A1B + 0,     A1B + 16384, 64);                           \
  asm volatile("s_waitcnt vmcnt(0)" ::: "memory");                                           \
  FENCE; BAR;                                                                                \
  DS_AF(afc, A0B, 0);                                                                        \
  DS_BF(bfA, B0B);                                                                           \
  for (int i = 0; i < NI; ++i) {                                                             \
    int kt0 = i << 7;                                                                        \
    int kt1 = kt0 + 64;                                                                      \
    int kt2 = kt0 + 128; if (kt2 >= K) kt2 -= K;                                             \
    int kt3 = kt0 + 192; if (kt3 >= K) kt3 -= K;                                             \
    PH(0, afc, afn, bfA, bfB, A0B, 1, B1B, VM2,                                              \
       STAGE(A,  row0 + 64,  row0 + 192, A1B + 8192,  A1B + 24576, kt1));                    \
    PH(1, afn, afc, bfA, bfB, A0B, 2, B1B, VM_NONE,                                          \
       STAGE(Bw, col0 + 0,   col0 + 64,  B0B + 0,     B0B + 8192,  kt2));                    \
    PH(2, afc, afn, bfA, bfB, A0B, 3, B1B, VM_NONE,                                          \
       STAGE(Bw, col0 + 128, col0 + 192, B0B + 16384, B0B + 24576, kt2));                    \
    PH(3, afn, afc, bfA, bfB, A1B, 0, B1B, VM6,                                              \
       STAGE(A,  row0 + 0,   row0 + 128, A0B + 0,     A0B + 16384, kt2));                    \
    PH(0, afc, afn, bfB, bfA, A1B, 1, B0B, VM2,                                              \
       STAGE(A,  row0 + 64,  row0 + 192, A0B + 8192,  A0B + 24576, kt2));                    \
    PH(1, afn, afc, bfB, bfA, A1B, 2, B0B, VM_NONE,                                          \
       STAGE(Bw, col0 + 0,   col0 + 64,  B1B + 0,     B1B + 8192,  kt3));                    \
    PH(2, afc, afn, bfB, bfA, A1B, 3, B0B, VM_NONE,                                          \
       STAGE(Bw, col0 + 128, col0 + 192, B1B + 16384, B1B + 24576, kt3));                    \
    PH(3, afn, afc, bfB, bfA, A0B, 0, B0B, VM6,                                              \
       STAGE(A,  row0 + 0,   row0 + 128, A1B + 0,     A1B + 16384, kt3));                    \
  }

// ---------------- GEMM1: h1 = relu(spine @ W1p^T + b1), packed 4-col stores ----------------
__global__ __launch_bounds__(512, 2) void gemm_h1(
    const unsigned short* __restrict__ A, const unsigned short* __restrict__ Bw,
    const float* __restrict__ bias, unsigned short* __restrict__ Cout,
    int K, int NI) {
  GEMM_BODY

#pragma unroll
  for (int m = 0; m < 8; ++m) {
    int gr0 = row0 + wr * 128 + m * 16 + kh * 4;
    int cb  = col0 + wc * 64 + lr * 4;
    float bv0 = bias[cb], bv1 = bias[cb + 1], bv2 = bias[cb + 2], bv3 = bias[cb + 3];
#pragma unroll
    for (int v = 0; v < 4; ++v) {
      unsigned lo = (unsigned)f2b(fmaxf(acc[m][0][v] + bv0, 0.f)) |
                    ((unsigned)f2b(fmaxf(acc[m][1][v] + bv1, 0.f)) << 16);
      unsigned hi = (unsigned)f2b(fmaxf(acc[m][2][v] + bv2, 0.f)) |
                    ((unsigned)f2b(fmaxf(acc[m][3][v] + bv3, 0.f)) << 16);
      *reinterpret_cast<uint2*>(&Cout[(size_t)(gr0 + v) * 2048 + cb]) = make_uint2(lo, hi);
    }
  }
}

// ---------------- GEMM2 + fused decoder + counter-gated reduction ----------------
// After K loop: relu'd tile -> swizzled LDS, per-wave mini-GEMM vs Weff -> out_part[nb].
// Then release-fence + atomicAdd(cnt[mband]); the 8th arriver sums all 8 partials,
// adds beff, tanh, writes d_out directly (deterministic: all partials identical
// regardless of arrival order). cnt zeroed per call via hipMemsetAsync.
__global__ __launch_bounds__(512, 2) void gemm_dec(
    const unsigned short* __restrict__ A, const unsigned short* __restrict__ Bw,
    const float* __restrict__ bias, const unsigned short* __restrict__ Weff,
    float* __restrict__ out_part, unsigned* __restrict__ cnt,
    const float* __restrict__ beff, float* __restrict__ out) {
  const int K = HID, NI = HID / 128;
  GEMM_BODY

  // drain in-flight gload_lds (last-iter wrapped stages still write LDS) + shadow reads
  asm volatile("s_waitcnt vmcnt(0)" ::: "memory");
  LGKM0;
  FENCE; BAR;

  // pack relu(acc+bias) -> LDS tile, row-major [r][c], byte = r*512 + (c*2 ^ ((r&7)<<4))
#pragma unroll
  for (int m = 0; m < 8; ++m) {
    int r0  = wr * 128 + m * 16 + kh * 4;
    int cbl = wc * 64 + lr * 4;
    float bv0 = bias[col0 + cbl], bv1 = bias[col0 + cbl + 1];
    float bv2 = bias[col0 + cbl + 2], bv3 = bias[col0 + cbl + 3];
#pragma unroll
    for (int v = 0; v < 4; ++v) {
      int r = r0 + v;
      unsigned lo = (unsigned)f2b(fmaxf(acc[m][0][v] + bv0, 0.f)) |
                    ((unsigned)f2b(fmaxf(acc[m][1][v] + bv1, 0.f)) << 16);
      unsigned hi = (unsigned)f2b(fmaxf(acc[m][2][v] + bv2, 0.f)) |
                    ((unsigned)f2b(fmaxf(acc[m][3][v] + bv3, 0.f)) << 16);
      int byte = r * 512 + ((cbl * 2) ^ ((r & 7) << 4));
      *reinterpret_cast<uint2*>(smem + byte) = make_uint2(lo, hi);
    }
  }
  FENCE; BAR;

  // decoder mini-GEMM: wave w owns rows [w*32, +32); partial[r][a] over this block's cols
  f32x4 acc2[2][2];
#pragma unroll
  for (int mf = 0; mf < 2; ++mf)
#pragma unroll
    for (int nf = 0; nf < 2; ++nf) acc2[mf][nf] = (f32x4){0.f, 0.f, 0.f, 0.f};

#pragma unroll
  for (int kt = 0; kt < 256; kt += 32) {
    bf16x8 aF[2], bF[2];
#pragma unroll
    for (int mf = 0; mf < 2; ++mf) {
      int r = w * 32 + mf * 16 + lr;
      aF[mf] = *reinterpret_cast<const bf16x8*>(
          smem + r * 512 + (((kt + kh * 8) * 2) ^ ((r & 7) << 4)));
    }
#pragma unroll
    for (int nf = 0; nf < 2; ++nf)
      bF[nf] = *reinterpret_cast<const bf16x8*>(
          Weff + (size_t)(nf * 16 + lr) * HID + col0 + kt + kh * 8);
#pragma unroll
    for (int mf = 0; mf < 2; ++mf)
#pragma unroll
      for (int nf = 0; nf < 2; ++nf)
        acc2[mf][nf] = __builtin_amdgcn_mfma_f32_16x16x32_bf16(aF[mf], bF[nf], acc2[mf][nf], 0, 0, 0);
  }

  const int nb = idx & 7;   // N-block slice
  float* op = out_part + (size_t)nb * BATCH * ADIM;
#pragma unroll
  for (int mf = 0; mf < 2; ++mf)
#pragma unroll
    for (int nf = 0; nf < 2; ++nf)
#pragma unroll
      for (int v = 0; v < 4; ++v) {
        int r = w * 32 + mf * 16 + kh * 4 + v;
        int a = nf * 16 + lr;
        op[(size_t)(row0 + r) * ADIM + a] = acc2[mf][nf][v];
      }

  // ---- counter-gated tail reduction ----
  __threadfence();                         // release: partials visible device-wide
  const int mband = xcd * 8 + (idx >> 3);  // 0..63
  volatile unsigned* flag = reinterpret_cast<volatile unsigned*>(smem);
  if (t == 0) {
    unsigned old = atomicAdd(&cnt[mband], 1u);
    *flag = (old == 7u) ? 1u : 0u;
  }
  __syncthreads();
  if (*flag) {
    __threadfence();                       // acquire: see all 8 partial sets
#pragma unroll
    for (int kk = 0; kk < 16; ++kk) {
      int i = kk * 512 + t;                // 8192 = 256 rows x 32 cols
      int r = i >> 5, a = i & 31;
      float s = beff[a];
#pragma unroll
      for (int nbq = 0; nbq < 8; ++nbq)
        s += out_part[((size_t)nbq * BATCH + row0 + r) * ADIM + a];
      out[(size_t)(row0 + r) * ADIM + a] = tanhf(s);
    }
  }
}

// ---------------- launch ----------------
extern "C" void kernel_launch(void* const* d_in, const int* in_sizes, int n_in,
                              void* d_out, int out_size, void* d_ws, size_t ws_size,
                              hipStream_t stream) {
  const float* state    = (const float*)d_in[0];
  const float* mean_enc = (const float*)d_in[1];
  const float* std_enc  = (const float*)d_in[2];
  const float* W1 = (const float*)d_in[3];
  const float* b1 = (const float*)d_in[4];
  const float* W2 = (const float*)d_in[5];
  const float* b2 = (const float*)d_in[6];
  const float* W3 = (const float*)d_in[7];
  const float* b3 = (const float*)d_in[8];
  const float* Wd = (const float*)d_in[9];
  const float* bd = (const float*)d_in[10];

  char* ws = (char*)d_ws;
  unsigned*       W1b   = (unsigned*)(ws + 0);                 //  5,242,880
  unsigned*       W2b   = (unsigned*)(ws + 5242880);           //  8,388,608
  unsigned short* Weff  = (unsigned short*)(ws + 13631488);    //    131,072
  float*          beff  = (float*)(ws + 13762560);             //        128
  unsigned*       cnt   = (unsigned*)(ws + 13762688);          //        256
  unsigned*       spine = (unsigned*)(ws + 13762944);          // 41,943,040
  unsigned short* h1    = (unsigned short*)(ws + 55705984);    // 67,108,864
  float*          part  = (float*)(ws + 122814848);            // 16,777,216 -> end ~140MB

  hipMemsetAsync(cnt, 0, 256, stream);   // zero completion counters every call

  prep_kernel<<<ENC_BLKS + W1_BLKS + W2_BLKS + WEFF_BLKS + 1, 256, 0, stream>>>(
      state, mean_enc, std_enc, W1, W2, W3, Wd, b3, bd,
      spine, W1b, W2b, Weff, beff);

  gemm_h1<<<512, 512, 0, stream>>>((const unsigned short*)spine, (const unsigned short*)W1b,
                                   b1, h1, KSPINE, KSPINE / 128);
  gemm_dec<<<512, 512, 0, stream>>>(h1, (const unsigned short*)W2b, b2, Weff, part,
                                    cnt, beff, (float*)d_out);
}

// Round 16
// 232.187 us; speedup vs baseline: 1.6122x; 1.6122x over previous
//
#include <hip/hip_runtime.h>
#include <hip/hip_bf16.h>
#include <stdint.h>

// ---------------- problem constants ----------------
#define BATCH   16384
#define SDIM    128
#define ENCK    10
#define ADIM    32
#define DECK    10
#define HID     2048
#define KSPINE  1280      // SDIM*ENCK

typedef __bf16 bf16x8 __attribute__((ext_vector_type(8)));
typedef float  f32x4  __attribute__((ext_vector_type(4)));

typedef __attribute__((address_space(1))) const void kGlobalVoid;
typedef __attribute__((address_space(3))) void       kLdsVoid;

__device__ __forceinline__ unsigned short f2b(float f) {
  union { float f; unsigned u; } v; v.f = f;
  unsigned r = v.u + 0x7fffu + ((v.u >> 16) & 1u);   // RNE
  return (unsigned short)(r >> 16);
}

// weight-row permutation within each 64-row group: position q holds original row
// (q&15)*4 + (q>>4).  Makes acc[m][n]@lane lr own 4 CONSECUTIVE output cols lr*4+n.
__device__ __forceinline__ int permrow(int pr) {
  int q = pr & 63;
  return (pr & ~63) | (((q & 15) << 2) | (q >> 4));
}

// ---------------- single fused prep: encoder + permuted W1/W2 f2b + Weff + beff ----------------
#define ENC_BLKS  40960
#define W1_BLKS   5120
#define W2_BLKS   8192
#define WEFF_BLKS 256

__global__ __launch_bounds__(256) void prep_kernel(
    const float* __restrict__ state, const float* __restrict__ mean,
    const float* __restrict__ stdv,
    const float* __restrict__ W1, const float* __restrict__ W2,
    const float* __restrict__ W3, const float* __restrict__ Wd,
    const float* __restrict__ b3, const float* __restrict__ bd,
    unsigned* __restrict__ spine, unsigned* __restrict__ W1b,
    unsigned* __restrict__ W2b, unsigned short* __restrict__ Weff,
    float* __restrict__ beff) {
  int b = blockIdx.x, t = threadIdx.x;
  if (b < ENC_BLKS) {                    // encoder: one thread per (b,d,k-pair)
    int idx = b * 256 + t;
    int idx1 = (int)(((long long)idx * 0x66666667LL) >> 33);  // idx/5
    int kk = idx - idx1 * 5;
    int d  = idx1 & (SDIM - 1);
    float x = state[idx1];
    int mi = d * ENCK + kk * 2;
    float m0 = mean[mi], m1 = mean[mi + 1];
    float s0 = stdv[mi], s1 = stdv[mi + 1];
    float v0 = 1.f / (1.f + __expf((m0 - x) / s0));
    float v1 = 1.f / (1.f + __expf((m1 - x) / s1));
    spine[idx] = (unsigned)f2b(v0) | ((unsigned)f2b(v1) << 16);
  } else if (b < ENC_BLKS + W1_BLKS) {   // W1 -> bf16, permuted rows (640 dwords/row)
    int i = (b - ENC_BLKS) * 256 + t;
    int row = i / 640, c2 = i - row * 640;
    float2 v = reinterpret_cast<const float2*>(W1)[permrow(row) * 640 + c2];
    W1b[i] = (unsigned)f2b(v.x) | ((unsigned)f2b(v.y) << 16);
  } else if (b < ENC_BLKS + W1_BLKS + W2_BLKS) {   // W2 -> bf16, permuted (1024 dw/row)
    int i = (b - ENC_BLKS - W1_BLKS) * 256 + t;
    int row = i >> 10, c2 = i & 1023;
    float2 v = reinterpret_cast<const float2*>(W2)[permrow(row) * 1024 + c2];
    W2b[i] = (unsigned)f2b(v.x) | ((unsigned)f2b(v.y) << 16);
  } else if (b < ENC_BLKS + W1_BLKS + W2_BLKS + WEFF_BLKS) {   // Weff (natural)
    int idx = (b - ENC_BLKS - W1_BLKS - W2_BLKS) * 256 + t;
    int a = idx >> 11, j = idx & 2047;
    float s = 0.f;
#pragma unroll
    for (int k = 0; k < DECK; ++k)
      s += Wd[a * DECK + k] * W3[(size_t)(a * DECK + k) * HID + j];
    Weff[idx] = f2b(s);
  } else {                               // beff
    if (t < ADIM) {
      float s = bd[t];
#pragma unroll
      for (int k = 0; k < DECK; ++k) s += Wd[t * DECK + k] * b3[t * DECK + k];
      beff[t] = s;
    }
  }
}

// ---------------- shared GEMM machinery (R7/R11 structure) ----------------
#define A0B 0
#define B0B 32768
#define A1B 65536
#define B1B 98304

#define FENCE asm volatile("" ::: "memory")
#define SB0 __builtin_amdgcn_sched_barrier(0)
#define BAR __builtin_amdgcn_s_barrier()
#define LGKM0 do { asm volatile("s_waitcnt lgkmcnt(0)" ::: "memory"); SB0; } while (0)

#define STAGE(BASEPTR, R0A, R0B, LDS0, LDS1, KT)                                             \
  __builtin_amdgcn_global_load_lds((kGlobalVoid*)((BASEPTR) + (size_t)((R0A) + rs) * K + (KT) + ce), \
                                   (kLdsVoid*)(smem + (LDS0) + t * 16), 16, 0, 0);           \
  __builtin_amdgcn_global_load_lds((kGlobalVoid*)((BASEPTR) + (size_t)((R0B) + rs) * K + (KT) + ce), \
                                   (kLdsVoid*)(smem + (LDS1) + t * 16), 16, 0, 0);

#define DS_AF(DST, ABASE, MPN)                                                               \
  _Pragma("unroll")                                                                          \
  for (int j2 = 0; j2 < 2; ++j2) {                                                           \
    _Pragma("unroll")                                                                        \
    for (int ks = 0; ks < 2; ++ks) {                                                         \
      int rowl = wr * 128 + (MPN) * 32 + j2 * 16 + lr;                                       \
      DST[j2][ks] = *reinterpret_cast<const bf16x8*>(                                        \
          smem + (ABASE) + rowl * 128 + ((((ks) << 6) | (kh << 4)) ^ swz));                  \
    }                                                                                        \
  }

#define DS_B2(DST, NP, BBASE)                                                                \
  _Pragma("unroll")                                                                          \
  for (int ks = 0; ks < 2; ++ks) {                                                           \
    int rowl = wc * 64 + (NP) * 16 + lr;                                                     \
    DST[NP][ks] = *reinterpret_cast<const bf16x8*>(                                          \
        smem + (BBASE) + rowl * 128 + ((((ks) << 6) | (kh << 4)) ^ swz));                    \
  }

#define DS_BF(DST, BBASE)                                                                    \
  _Pragma("unroll")                                                                          \
  for (int n = 0; n < 4; ++n) {                                                              \
    _Pragma("unroll")                                                                        \
    for (int ks = 0; ks < 2; ++ks) {                                                         \
      int rowl = wc * 64 + n * 16 + lr;                                                      \
      DST[n][ks] = *reinterpret_cast<const bf16x8*>(                                         \
          smem + (BBASE) + rowl * 128 + ((((ks) << 6) | (kh << 4)) ^ swz));                  \
    }                                                                                        \
  }

#define MFMA16(MP, AF, BF)                                                                   \
  _Pragma("unroll")                                                                          \
  for (int j2 = 0; j2 < 2; ++j2)                                                             \
    _Pragma("unroll")                                                                        \
    for (int n = 0; n < 4; ++n)                                                              \
      _Pragma("unroll")                                                                      \
      for (int ks = 0; ks < 2; ++ks)                                                         \
        acc[(MP) * 2 + j2][n] = __builtin_amdgcn_mfma_f32_16x16x32_bf16(                     \
            AF[j2][ks], BF[n][ks], acc[(MP) * 2 + j2][n], 0, 0, 0);

#define SGB_PHASE                                                                            \
  __builtin_amdgcn_sched_group_barrier(0x8, 2, 0);                                           \
  __builtin_amdgcn_sched_group_barrier(0x100, 1, 0);                                         \
  __builtin_amdgcn_sched_group_barrier(0x8, 2, 0);                                           \
  __builtin_amdgcn_sched_group_barrier(0x100, 1, 0);                                         \
  __builtin_amdgcn_sched_group_barrier(0x20, 2, 0);                                          \
  __builtin_amdgcn_sched_group_barrier(0x8, 3, 0);                                           \
  __builtin_amdgcn_sched_group_barrier(0x100, 1, 0);                                         \
  __builtin_amdgcn_sched_group_barrier(0x8, 3, 0);                                           \
  __builtin_amdgcn_sched_group_barrier(0x100, 1, 0);                                         \
  __builtin_amdgcn_sched_group_barrier(0x8, 3, 0);                                           \
  __builtin_amdgcn_sched_group_barrier(0x100, 1, 0);                                         \
  __builtin_amdgcn_sched_group_barrier(0x8, 3, 0);                                           \
  __builtin_amdgcn_sched_group_barrier(0x100, 1, 0);

#define VM_NONE
#define VM2 asm volatile("s_waitcnt vmcnt(2)" ::: "memory"); SB0;
#define VM6 asm volatile("s_waitcnt vmcnt(6)" ::: "memory"); SB0;

#define PH(MP, AF_C, AF_N, BF_C, BF_N, NXT_A, NXT_MP, BBASE_N, VMW, STG)                     \
  do {                                                                                       \
    LGKM0;                                                                                   \
    VMW                                                                                      \
    __builtin_amdgcn_s_setprio(1);                                                           \
    MFMA16(MP, AF_C, BF_C);                                                                  \
    __builtin_amdgcn_s_setprio(0);                                                           \
    DS_AF(AF_N, NXT_A, NXT_MP);                                                              \
    DS_B2(BF_N, MP, BBASE_N);                                                                \
    STG;                                                                                     \
    SGB_PHASE;                                                                               \
    FENCE;                                                                                   \
    BAR;                                                                                     \
  } while (0)

// head + prologue + main K loop; leaves acc ready. Expects A, Bw, K, NI in scope.
#define GEMM_BODY                                                                            \
  __shared__ char smem[131072];                                                              \
  const int t    = threadIdx.x;                                                              \
  const int lane = t & 63;                                                                   \
  const int w    = t >> 6;                                                                   \
  const int wr   = w >> 2;                                                                   \
  const int wc   = w & 3;                                                                    \
  const int lr   = lane & 15;                                                                \
  const int kh   = lane >> 4;                                                                \
  const int swz  = (lr & 7) << 4;                                                            \
  const int rs   = t >> 3;                                                                   \
  const int ce   = ((t & 7) ^ (rs & 7)) << 3;                                                \
  const int bid = blockIdx.x;                                                                \
  const int xcd = bid & 7, idx = bid >> 3;                                                   \
  const int row0 = (xcd * 8 + (idx >> 3)) * 256;                                             \
  const int col0 = (idx & 7) * 256;                                                          \
  f32x4 acc[8][4];                                                                           \
  _Pragma("unroll")                                                                          \
  for (int m = 0; m < 8; ++m)                                                                \
    _Pragma("unroll")                                                                        \
    for (int n = 0; n < 4; ++n)                                                              \
      acc[m][n] = (f32x4){0.f, 0.f, 0.f, 0.f};                                               \
  bf16x8 afc[2][2], afn[2][2], bfA[4][2], bfB[4][2];                                         \
  STAGE(Bw, col0 + 0,   col0 + 64,  B0B + 0,     B0B + 8192,  0);                            \
  STAGE(Bw, col0 + 128, col0 + 192, B0B + 16384, B0B + 24576, 0);                            \
  STAGE(A,  row0 + 0,   row0 + 128, A0B + 0,     A0B + 16384, 0);                            \
  STAGE(A,  row0 + 64,  row0 + 192, A0B + 8192,  A0B + 24576, 0);                            \
  STAGE(Bw, col0 + 0,   col0 + 64,  B1B + 0,     B1B + 8192,  64);                           \
  STAGE(Bw, col0 + 128, col0 + 192, B1B + 16384, B1B + 24576, 64);                           \
  STAGE(A,  row0 + 0,   row0 + 128, A1B + 0,     A1B + 16384, 64);                           \
  asm volatile("s_waitcnt vmcnt(0)" ::: "memory");                                           \
  FENCE; BAR;                                                                                \
  DS_AF(afc, A0B, 0);                                                                        \
  DS_BF(bfA, B0B);                                                                           \
  for (int i = 0; i < NI; ++i) {                                                             \
    int kt0 = i << 7;                                                                        \
    int kt1 = kt0 + 64;                                                                      \
    int kt2 = kt0 + 128; if (kt2 >= K) kt2 -= K;                                             \
    int kt3 = kt0 + 192; if (kt3 >= K) kt3 -= K;                                             \
    PH(0, afc, afn, bfA, bfB, A0B, 1, B1B, VM2,                                              \
       STAGE(A,  row0 + 64,  row0 + 192, A1B + 8192,  A1B + 24576, kt1));                    \
    PH(1, afn, afc, bfA, bfB, A0B, 2, B1B, VM_NONE,                                          \
       STAGE(Bw, col0 + 0,   col0 + 64,  B0B + 0,     B0B + 8192,  kt2));                    \
    PH(2, afc, afn, bfA, bfB, A0B, 3, B1B, VM_NONE,                                          \
       STAGE(Bw, col0 + 128, col0 + 192, B0B + 16384, B0B + 24576, kt2));                    \
    PH(3, afn, afc, bfA, bfB, A1B, 0, B1B, VM6,                                              \
       STAGE(A,  row0 + 0,   row0 + 128, A0B + 0,     A0B + 16384, kt2));                    \
    PH(0, afc, afn, bfB, bfA, A1B, 1, B0B, VM2,                                              \
       STAGE(A,  row0 + 64,  row0 + 192, A0B + 8192,  A0B + 24576, kt2));                    \
    PH(1, afn, afc, bfB, bfA, A1B, 2, B0B, VM_NONE,                                          \
       STAGE(Bw, col0 + 0,   col0 + 64,  B1B + 0,     B1B + 8192,  kt3));                    \
    PH(2, afc, afn, bfB, bfA, A1B, 3, B0B, VM_NONE,                                          \
       STAGE(Bw, col0 + 128, col0 + 192, B1B + 16384, B1B + 24576, kt3));                    \
    PH(3, afn, afc, bfB, bfA, A0B, 0, B0B, VM6,                                              \
       STAGE(A,  row0 + 0,   row0 + 128, A1B + 0,     A1B + 16384, kt3));                    \
  }

// ---------------- GEMM1: h1 = relu(spine @ W1p^T + b1), packed 4-col stores ----------------
__global__ __launch_bounds__(512, 2) void gemm_h1(
    const unsigned short* __restrict__ A, const unsigned short* __restrict__ Bw,
    const float* __restrict__ bias, unsigned short* __restrict__ Cout,
    int K, int NI) {
  GEMM_BODY

#pragma unroll
  for (int m = 0; m < 8; ++m) {
    int gr0 = row0 + wr * 128 + m * 16 + kh * 4;
    int cb  = col0 + wc * 64 + lr * 4;
    float bv0 = bias[cb], bv1 = bias[cb + 1], bv2 = bias[cb + 2], bv3 = bias[cb + 3];
#pragma unroll
    for (int v = 0; v < 4; ++v) {
      unsigned lo = (unsigned)f2b(fmaxf(acc[m][0][v] + bv0, 0.f)) |
                    ((unsigned)f2b(fmaxf(acc[m][1][v] + bv1, 0.f)) << 16);
      unsigned hi = (unsigned)f2b(fmaxf(acc[m][2][v] + bv2, 0.f)) |
                    ((unsigned)f2b(fmaxf(acc[m][3][v] + bv3, 0.f)) << 16);
      *reinterpret_cast<uint2*>(&Cout[(size_t)(gr0 + v) * 2048 + cb]) = make_uint2(lo, hi);
    }
  }
}

// ---------------- GEMM2 + fused decoder: out_part[nb][r][a] (nontemporal stores) ----------------
__global__ __launch_bounds__(512, 2) void gemm_dec(
    const unsigned short* __restrict__ A, const unsigned short* __restrict__ Bw,
    const float* __restrict__ bias, const unsigned short* __restrict__ Weff,
    float* __restrict__ out_part) {
  const int K = HID, NI = HID / 128;
  GEMM_BODY

  // drain in-flight gload_lds (last-iter wrapped stages still write LDS) + shadow reads
  asm volatile("s_waitcnt vmcnt(0)" ::: "memory");
  LGKM0;
  FENCE; BAR;

  // pack relu(acc+bias) -> LDS tile, row-major [r][c], byte = r*512 + (c*2 ^ ((r&7)<<4))
#pragma unroll
  for (int m = 0; m < 8; ++m) {
    int r0  = wr * 128 + m * 16 + kh * 4;
    int cbl = wc * 64 + lr * 4;
    float bv0 = bias[col0 + cbl], bv1 = bias[col0 + cbl + 1];
    float bv2 = bias[col0 + cbl + 2], bv3 = bias[col0 + cbl + 3];
#pragma unroll
    for (int v = 0; v < 4; ++v) {
      int r = r0 + v;
      unsigned lo = (unsigned)f2b(fmaxf(acc[m][0][v] + bv0, 0.f)) |
                    ((unsigned)f2b(fmaxf(acc[m][1][v] + bv1, 0.f)) << 16);
      unsigned hi = (unsigned)f2b(fmaxf(acc[m][2][v] + bv2, 0.f)) |
                    ((unsigned)f2b(fmaxf(acc[m][3][v] + bv3, 0.f)) << 16);
      int byte = r * 512 + ((cbl * 2) ^ ((r & 7) << 4));
      *reinterpret_cast<uint2*>(smem + byte) = make_uint2(lo, hi);
    }
  }
  FENCE; BAR;

  // decoder mini-GEMM: wave w owns rows [w*32, +32); partial[r][a] over this block's cols
  f32x4 acc2[2][2];
#pragma unroll
  for (int mf = 0; mf < 2; ++mf)
#pragma unroll
    for (int nf = 0; nf < 2; ++nf) acc2[mf][nf] = (f32x4){0.f, 0.f, 0.f, 0.f};

#pragma unroll
  for (int kt = 0; kt < 256; kt += 32) {
    bf16x8 aF[2], bF[2];
#pragma unroll
    for (int mf = 0; mf < 2; ++mf) {
      int r = w * 32 + mf * 16 + lr;
      aF[mf] = *reinterpret_cast<const bf16x8*>(
          smem + r * 512 + (((kt + kh * 8) * 2) ^ ((r & 7) << 4)));
    }
#pragma unroll
    for (int nf = 0; nf < 2; ++nf)
      bF[nf] = *reinterpret_cast<const bf16x8*>(
          Weff + (size_t)(nf * 16 + lr) * HID + col0 + kt + kh * 8);
#pragma unroll
    for (int mf = 0; mf < 2; ++mf)
#pragma unroll
      for (int nf = 0; nf < 2; ++nf)
        acc2[mf][nf] = __builtin_amdgcn_mfma_f32_16x16x32_bf16(aF[mf], bF[nf], acc2[mf][nf], 0, 0, 0);
  }

  const int nb = idx & 7;   // N-block slice
  float* op = out_part + (size_t)nb * BATCH * ADIM;
#pragma unroll
  for (int mf = 0; mf < 2; ++mf)
#pragma unroll
    for (int nf = 0; nf < 2; ++nf)
#pragma unroll
      for (int v = 0; v < 4; ++v) {
        int r = w * 32 + mf * 16 + kh * 4 + v;
        int a = nf * 16 + lr;
        __builtin_nontemporal_store(acc2[mf][nf][v],
                                    &op[(size_t)(row0 + r) * ADIM + a]);
      }
}

// ---------------- reduce: out = tanh(sum_8 partials + beff) ----------------
__global__ __launch_bounds__(256) void reduce_tanh(
    const float* __restrict__ part, const float* __restrict__ beff,
    float* __restrict__ out) {
  int i = blockIdx.x * 256 + threadIdx.x;   // < BATCH*ADIM
  float s = beff[i & 31];
#pragma unroll
  for (int nb = 0; nb < 8; ++nb)
    s += __builtin_nontemporal_load(&part[(size_t)nb * BATCH * ADIM + i]);
  out[i] = tanhf(s);
}

// ---------------- launch ----------------
extern "C" void kernel_launch(void* const* d_in, const int* in_sizes, int n_in,
                              void* d_out, int out_size, void* d_ws, size_t ws_size,
                              hipStream_t stream) {
  const float* state    = (const float*)d_in[0];
  const float* mean_enc = (const float*)d_in[1];
  const float* std_enc  = (const float*)d_in[2];
  const float* W1 = (const float*)d_in[3];
  const float* b1 = (const float*)d_in[4];
  const float* W2 = (const float*)d_in[5];
  const float* b2 = (const float*)d_in[6];
  const float* W3 = (const float*)d_in[7];
  const float* b3 = (const float*)d_in[8];
  const float* Wd = (const float*)d_in[9];
  const float* bd = (const float*)d_in[10];

  char* ws = (char*)d_ws;
  unsigned*       W1b   = (unsigned*)(ws + 0);                 //  5,242,880
  unsigned*       W2b   = (unsigned*)(ws + 5242880);           //  8,388,608
  unsigned short* Weff  = (unsigned short*)(ws + 13631488);    //    131,072
  float*          beff  = (float*)(ws + 13762560);             //        128
  unsigned*       spine = (unsigned*)(ws + 13762688);          // 41,943,040
  unsigned short* h1    = (unsigned short*)(ws + 55705728);    // 67,108,864
  float*          part  = (float*)(ws + 122814592);            // 16,777,216 -> end ~140MB

  prep_kernel<<<ENC_BLKS + W1_BLKS + W2_BLKS + WEFF_BLKS + 1, 256, 0, stream>>>(
      state, mean_enc, std_enc, W1, W2, W3, Wd, b3, bd,
      spine, W1b, W2b, Weff, beff);

  gemm_h1<<<512, 512, 0, stream>>>((const unsigned short*)spine, (const unsigned short*)W1b,
                                   b1, h1, KSPINE, KSPINE / 128);
  gemm_dec<<<512, 512, 0, stream>>>(h1, (const unsigned short*)W2b, b2, Weff, part);
  reduce_tanh<<<(BATCH * ADIM) / 256, 256, 0, stream>>>(part, beff, (float*)d_out);
}